// Round 1
// baseline (396.404 us; speedup 1.0000x reference)
//
#include <hip/hip_runtime.h>

// TinyMambaMulti: B=4, L=4096, D_MODEL=64, D_INNER=128, D_STATE=16, DT_RANK=4,
// D_CONV=4, N_LAYERS=2, OUT=6. All fp32.

#define NB 4
#define SL 4096
#define BLR (NB*SL)      // 16384 rows
#define NC 64            // scan chunks per sequence
#define CT 64            // steps per chunk (NC*CT == SL)

__device__ __forceinline__ float siluf(float x) { return x / (1.f + __expf(-x)); }
__device__ __forceinline__ float softplusf(float x) { return x > 20.f ? x : log1pf(__expf(x)); }

// ---------------- linear_in: h[r][64] = x[r][57] @ w[64][57]^T + b ----------------
__global__ __launch_bounds__(256) void k_linin(const float* __restrict__ x, const float* __restrict__ w,
                                               const float* __restrict__ bias, float* __restrict__ h) {
  __shared__ __align__(16) float xs[64][60];
  __shared__ __align__(16) float ws[64][60];
  const int t = threadIdx.x;
  const int r0 = blockIdx.x * 64;
  for (int i = t; i < 64 * 57; i += 256) {
    int r = i / 57, k = i - r * 57;
    xs[r][k] = x[(r0 + r) * 57 + k];
    ws[r][k] = w[i];
  }
  for (int i = t; i < 64 * 3; i += 256) {
    int r = i / 3, j = i - r * 3;
    xs[r][57 + j] = 0.f;
    ws[r][57 + j] = 0.f;
  }
  __syncthreads();
  const int col = t & 63;
  const int rg = t >> 6;   // 4 row groups of 16 rows
  float wreg[15][4];
#pragma unroll
  for (int k4 = 0; k4 < 15; ++k4) {
    float4 v = *(const float4*)&ws[col][k4 * 4];
    wreg[k4][0] = v.x; wreg[k4][1] = v.y; wreg[k4][2] = v.z; wreg[k4][3] = v.w;
  }
  const float bcol = bias[col];
  for (int g = 0; g < 4; ++g) {
    const int rb = rg * 16 + g * 4;
    float acc[4] = {bcol, bcol, bcol, bcol};
#pragma unroll
    for (int k4 = 0; k4 < 15; ++k4) {
#pragma unroll
      for (int i = 0; i < 4; ++i) {
        float4 xv = *(const float4*)&xs[rb + i][k4 * 4];
        acc[i] = fmaf(xv.x, wreg[k4][0], acc[i]);
        acc[i] = fmaf(xv.y, wreg[k4][1], acc[i]);
        acc[i] = fmaf(xv.z, wreg[k4][2], acc[i]);
        acc[i] = fmaf(xv.w, wreg[k4][3], acc[i]);
      }
    }
#pragma unroll
    for (int i = 0; i < 4; ++i) h[(r0 + rb + i) * 64 + col] = acc[i];
  }
}

// ---------------- in_proj: [16384x256] = h[16384x64] @ W[256x64]^T, split xp/z ----------------
__global__ __launch_bounds__(256) void k_inproj(const float* __restrict__ hin, const float* __restrict__ W,
                                                float* __restrict__ xp, float* __restrict__ z) {
  __shared__ __align__(16) float ht[64][68];
  __shared__ __align__(16) float wt[64][68];
  const int t = threadIdx.x;
  const int r0 = blockIdx.x * 64;
  const int c0 = blockIdx.y * 64;
  for (int idx = t; idx < 64 * 16; idx += 256) {
    int r = idx >> 4, k4 = idx & 15;
    float4 v = *(const float4*)(hin + (r0 + r) * 64 + 4 * k4);
    ht[4 * k4 + 0][r] = v.x; ht[4 * k4 + 1][r] = v.y; ht[4 * k4 + 2][r] = v.z; ht[4 * k4 + 3][r] = v.w;
  }
  for (int idx = t; idx < 64 * 16; idx += 256) {
    int c = idx >> 4, k4 = idx & 15;
    float4 v = *(const float4*)(W + (c0 + c) * 64 + 4 * k4);
    wt[4 * k4 + 0][c] = v.x; wt[4 * k4 + 1][c] = v.y; wt[4 * k4 + 2][c] = v.z; wt[4 * k4 + 3][c] = v.w;
  }
  __syncthreads();
  const int tc = t & 15, tr = t >> 4;
  float acc[4][4] = {};
  for (int k = 0; k < 64; ++k) {
    float4 a = *(const float4*)&ht[k][4 * tr];
    float4 b = *(const float4*)&wt[k][4 * tc];
    float av[4] = {a.x, a.y, a.z, a.w};
    float bv[4] = {b.x, b.y, b.z, b.w};
#pragma unroll
    for (int i = 0; i < 4; ++i)
#pragma unroll
      for (int j = 0; j < 4; ++j) acc[i][j] = fmaf(av[i], bv[j], acc[i][j]);
  }
#pragma unroll
  for (int i = 0; i < 4; ++i) {
    int row = r0 + 4 * tr + i;
    int c = c0 + 4 * tc;
    float4 v = make_float4(acc[i][0], acc[i][1], acc[i][2], acc[i][3]);
    if (c0 < 128) *(float4*)(xp + row * 128 + c) = v;
    else          *(float4*)(z + row * 128 + (c - 128)) = v;
  }
}

// ---------------- depthwise causal conv (k=4) + silu ----------------
__global__ __launch_bounds__(256) void k_conv(const float* __restrict__ xp, const float* __restrict__ cw,
                                              const float* __restrict__ cb, float* __restrict__ u) {
  int i = blockIdx.x * 256 + threadIdx.x;   // over BLR*128
  int d = i & 127;
  int row = i >> 7;
  int l = row & (SL - 1);
  const float4 wv = *(const float4*)(cw + d * 4);
  const float* base = xp + (size_t)row * 128 + d;
  float acc = cb[d] + base[0] * wv.w;
  if (l >= 1) acc += base[-128] * wv.z;
  if (l >= 2) acc += base[-256] * wv.y;
  if (l >= 3) acc += base[-384] * wv.x;
  u[i] = siluf(acc);
}

// ---------------- x_proj (36 outs) + dt_proj + softplus ----------------
__global__ __launch_bounds__(256) void k_xproj(const float* __restrict__ u, const float* __restrict__ xpw,
                                               const float* __restrict__ dpw, const float* __restrict__ dpb,
                                               float* __restrict__ delta, float* __restrict__ Bm,
                                               float* __restrict__ Cm) {
  __shared__ __align__(16) float us[32][132];
  __shared__ __align__(16) float ws[36][132];
  __shared__ float dbl[32][40];
  const int t = threadIdx.x;
  const int r0 = blockIdx.x * 32;
  for (int idx = t; idx < 32 * 32; idx += 256) {
    int r = idx >> 5, k4 = idx & 31;
    *(float4*)&us[r][4 * k4] = *(const float4*)(u + (size_t)(r0 + r) * 128 + 4 * k4);
  }
  for (int idx = t; idx < 36 * 32; idx += 256) {
    int c = idx >> 5, k4 = idx & 31;
    *(float4*)&ws[c][4 * k4] = *(const float4*)(xpw + c * 128 + 4 * k4);
  }
  __syncthreads();
  // dbl[32][36]: each task = 1 row x 4 cols
  for (int idx = t; idx < 32 * 9; idx += 256) {
    int r = idx / 9, cg = idx - r * 9;
    int c = cg * 4;
    float a0 = 0, a1 = 0, a2 = 0, a3 = 0;
#pragma unroll 8
    for (int k4 = 0; k4 < 32; ++k4) {
      float4 uu = *(const float4*)&us[r][4 * k4];
      float4 w0 = *(const float4*)&ws[c + 0][4 * k4];
      float4 w1 = *(const float4*)&ws[c + 1][4 * k4];
      float4 w2 = *(const float4*)&ws[c + 2][4 * k4];
      float4 w3 = *(const float4*)&ws[c + 3][4 * k4];
      a0 += uu.x * w0.x + uu.y * w0.y + uu.z * w0.z + uu.w * w0.w;
      a1 += uu.x * w1.x + uu.y * w1.y + uu.z * w1.z + uu.w * w1.w;
      a2 += uu.x * w2.x + uu.y * w2.y + uu.z * w2.z + uu.w * w2.w;
      a3 += uu.x * w3.x + uu.y * w3.y + uu.z * w3.z + uu.w * w3.w;
    }
    dbl[r][c + 0] = a0; dbl[r][c + 1] = a1; dbl[r][c + 2] = a2; dbl[r][c + 3] = a3;
  }
  __syncthreads();
  for (int idx = t; idx < 32 * 16; idx += 256) {
    int r = idx >> 4, n = idx & 15;
    int row = r0 + r;
    Bm[row * 16 + n] = dbl[r][4 + n];
    Cm[row * 16 + n] = dbl[r][20 + n];
  }
  for (int idx = t; idx < 32 * 128; idx += 256) {
    int r = idx >> 7, dd = idx & 127;
    float4 wv = *(const float4*)(dpw + dd * 4);
    float acc = dpb[dd] + dbl[r][0] * wv.x + dbl[r][1] * wv.y + dbl[r][2] * wv.z + dbl[r][3] * wv.w;
    delta[(size_t)(r0 + r) * 128 + dd] = softplusf(acc);
  }
}

// ---------------- scan phase 1: per-chunk decay product + local state ----------------
__global__ __launch_bounds__(256) void k_scan1(const float* __restrict__ delta, const float* __restrict__ u,
                                               const float* __restrict__ Bm, const float* __restrict__ Alog,
                                               float* __restrict__ chP, float* __restrict__ chH) {
  int tid = blockIdx.x * 256 + threadIdx.x;      // 4*NC*128 = 32768
  const int d = tid & 127, c = (tid >> 7) & (NC - 1), b = tid >> 13;
  float A[16], P[16], hst[16];
  {
    float4 a0 = *(const float4*)(Alog + d * 16 + 0);
    float4 a1 = *(const float4*)(Alog + d * 16 + 4);
    float4 a2 = *(const float4*)(Alog + d * 16 + 8);
    float4 a3 = *(const float4*)(Alog + d * 16 + 12);
    float av[16] = {a0.x, a0.y, a0.z, a0.w, a1.x, a1.y, a1.z, a1.w,
                    a2.x, a2.y, a2.z, a2.w, a3.x, a3.y, a3.z, a3.w};
#pragma unroll
    for (int n = 0; n < 16; ++n) { A[n] = -__expf(av[n]); P[n] = 1.f; hst[n] = 0.f; }
  }
  const int rbase = b * SL + c * CT;
  for (int tt = 0; tt < CT; ++tt) {
    int row = rbase + tt;
    float dt = delta[(size_t)row * 128 + d];
    float du = dt * u[(size_t)row * 128 + d];
    float4 B0 = *(const float4*)(Bm + row * 16 + 0);
    float4 B1 = *(const float4*)(Bm + row * 16 + 4);
    float4 B2 = *(const float4*)(Bm + row * 16 + 8);
    float4 B3 = *(const float4*)(Bm + row * 16 + 12);
    float Bv[16] = {B0.x, B0.y, B0.z, B0.w, B1.x, B1.y, B1.z, B1.w,
                    B2.x, B2.y, B2.z, B2.w, B3.x, B3.y, B3.z, B3.w};
#pragma unroll
    for (int n = 0; n < 16; ++n) {
      float a = __expf(dt * A[n]);
      hst[n] = fmaf(a, hst[n], du * Bv[n]);
      P[n] *= a;
    }
  }
  int off = ((b * 128 + d) * NC + c) * 16;
#pragma unroll
  for (int n4 = 0; n4 < 4; ++n4) {
    *(float4*)(chP + off + 4 * n4) = make_float4(P[4 * n4], P[4 * n4 + 1], P[4 * n4 + 2], P[4 * n4 + 3]);
    *(float4*)(chH + off + 4 * n4) = make_float4(hst[4 * n4], hst[4 * n4 + 1], hst[4 * n4 + 2], hst[4 * n4 + 3]);
  }
}

// ---------------- scan phase 2: carry propagation across chunks ----------------
__global__ __launch_bounds__(256) void k_scan2(const float* __restrict__ chP, const float* __restrict__ chH,
                                               float* __restrict__ cin) {
  int tid = blockIdx.x * 256 + threadIdx.x;  // 8192
  int n = tid & 15, d = (tid >> 4) & 127, b = tid >> 11;
  float carry = 0.f;
  int base = (b * 128 + d) * NC * 16 + n;
#pragma unroll 4
  for (int c = 0; c < NC; ++c) {
    int idx = base + c * 16;
    cin[idx] = carry;
    carry = fmaf(chP[idx], carry, chH[idx]);
  }
}

// ---------------- scan phase 3: replay with carry, emit y = (scan + u*D) * silu(z) ----------------
__global__ __launch_bounds__(256) void k_scan3(const float* __restrict__ delta, const float* __restrict__ u,
                                               const float* __restrict__ Bm, const float* __restrict__ Cm,
                                               const float* __restrict__ zb, const float* __restrict__ cin,
                                               const float* __restrict__ Alog, const float* __restrict__ Dsk,
                                               float* __restrict__ y) {
  int tid = blockIdx.x * 256 + threadIdx.x;
  const int d = tid & 127, c = (tid >> 7) & (NC - 1), b = tid >> 13;
  float A[16], hst[16];
  {
    float4 a0 = *(const float4*)(Alog + d * 16 + 0);
    float4 a1 = *(const float4*)(Alog + d * 16 + 4);
    float4 a2 = *(const float4*)(Alog + d * 16 + 8);
    float4 a3 = *(const float4*)(Alog + d * 16 + 12);
    float av[16] = {a0.x, a0.y, a0.z, a0.w, a1.x, a1.y, a1.z, a1.w,
                    a2.x, a2.y, a2.z, a2.w, a3.x, a3.y, a3.z, a3.w};
#pragma unroll
    for (int n = 0; n < 16; ++n) A[n] = -__expf(av[n]);
  }
  int off = ((b * 128 + d) * NC + c) * 16;
  {
    float4 h0 = *(const float4*)(cin + off + 0);
    float4 h1 = *(const float4*)(cin + off + 4);
    float4 h2 = *(const float4*)(cin + off + 8);
    float4 h3 = *(const float4*)(cin + off + 12);
    hst[0] = h0.x; hst[1] = h0.y; hst[2] = h0.z; hst[3] = h0.w;
    hst[4] = h1.x; hst[5] = h1.y; hst[6] = h1.z; hst[7] = h1.w;
    hst[8] = h2.x; hst[9] = h2.y; hst[10] = h2.z; hst[11] = h2.w;
    hst[12] = h3.x; hst[13] = h3.y; hst[14] = h3.z; hst[15] = h3.w;
  }
  const float Dd = Dsk[d];
  const int rbase = b * SL + c * CT;
  for (int tt = 0; tt < CT; ++tt) {
    int row = rbase + tt;
    float dt = delta[(size_t)row * 128 + d];
    float ut = u[(size_t)row * 128 + d];
    float du = dt * ut;
    float4 B0 = *(const float4*)(Bm + row * 16 + 0);
    float4 B1 = *(const float4*)(Bm + row * 16 + 4);
    float4 B2 = *(const float4*)(Bm + row * 16 + 8);
    float4 B3 = *(const float4*)(Bm + row * 16 + 12);
    float4 C0 = *(const float4*)(Cm + row * 16 + 0);
    float4 C1 = *(const float4*)(Cm + row * 16 + 4);
    float4 C2 = *(const float4*)(Cm + row * 16 + 8);
    float4 C3 = *(const float4*)(Cm + row * 16 + 12);
    float Bv[16] = {B0.x, B0.y, B0.z, B0.w, B1.x, B1.y, B1.z, B1.w,
                    B2.x, B2.y, B2.z, B2.w, B3.x, B3.y, B3.z, B3.w};
    float Cv[16] = {C0.x, C0.y, C0.z, C0.w, C1.x, C1.y, C1.z, C1.w,
                    C2.x, C2.y, C2.z, C2.w, C3.x, C3.y, C3.z, C3.w};
    float yt = 0.f;
#pragma unroll
    for (int n = 0; n < 16; ++n) {
      float a = __expf(dt * A[n]);
      hst[n] = fmaf(a, hst[n], du * Bv[n]);
      yt = fmaf(hst[n], Cv[n], yt);
    }
    float zv = zb[(size_t)row * 128 + d];
    y[(size_t)row * 128 + d] = (yt + ut * Dd) * siluf(zv);
  }
}

// ---------------- out_proj (K=128 -> 64) with residual accumulate into h ----------------
__global__ __launch_bounds__(256) void k_outproj(const float* __restrict__ y, const float* __restrict__ W,
                                                 float* __restrict__ hio) {
  __shared__ __align__(16) float yt[128][68];
  __shared__ __align__(16) float wt[128][68];
  const int t = threadIdx.x;
  const int r0 = blockIdx.x * 64;
  for (int idx = t; idx < 64 * 32; idx += 256) {
    int r = idx >> 5, k4 = idx & 31;
    float4 v = *(const float4*)(y + (size_t)(r0 + r) * 128 + 4 * k4);
    yt[4 * k4 + 0][r] = v.x; yt[4 * k4 + 1][r] = v.y; yt[4 * k4 + 2][r] = v.z; yt[4 * k4 + 3][r] = v.w;
  }
  for (int idx = t; idx < 64 * 32; idx += 256) {
    int c = idx >> 5, k4 = idx & 31;
    float4 v = *(const float4*)(W + c * 128 + 4 * k4);
    wt[4 * k4 + 0][c] = v.x; wt[4 * k4 + 1][c] = v.y; wt[4 * k4 + 2][c] = v.z; wt[4 * k4 + 3][c] = v.w;
  }
  __syncthreads();
  const int tc = t & 15, tr = t >> 4;
  float acc[4][4] = {};
  for (int k = 0; k < 128; ++k) {
    float4 a = *(const float4*)&yt[k][4 * tr];
    float4 b = *(const float4*)&wt[k][4 * tc];
    float av[4] = {a.x, a.y, a.z, a.w};
    float bv[4] = {b.x, b.y, b.z, b.w};
#pragma unroll
    for (int i = 0; i < 4; ++i)
#pragma unroll
      for (int j = 0; j < 4; ++j) acc[i][j] = fmaf(av[i], bv[j], acc[i][j]);
  }
#pragma unroll
  for (int i = 0; i < 4; ++i) {
    int row = r0 + 4 * tr + i;
    float4* p = (float4*)(hio + row * 64 + 4 * tc);
    float4 old = *p;
    *p = make_float4(old.x + acc[i][0], old.y + acc[i][1], old.z + acc[i][2], old.w + acc[i][3]);
  }
}

// ---------------- pooling partials over L ----------------
__global__ __launch_bounds__(256) void k_poolpart(const float* __restrict__ h, float* __restrict__ pp) {
  const int lb = blockIdx.x;   // 0..31
  const int b = blockIdx.y;    // 0..3
  const int t = threadIdx.x;
  const int d = t & 63, part = t >> 6;
  float s = 0.f;
  for (int i = 0; i < 32; ++i) {
    int l = lb * 128 + part + i * 4;
    s += h[(size_t)(b * SL + l) * 64 + d];
  }
  __shared__ float red[256];
  red[t] = s;
  __syncthreads();
  if (t < 64) pp[(b * 32 + lb) * 64 + t] = red[t] + red[t + 64] + red[t + 128] + red[t + 192];
}

// ---------------- final reduce + classifier ----------------
__global__ __launch_bounds__(256) void k_cls(const float* __restrict__ pp, const float* __restrict__ wc,
                                             const float* __restrict__ bc, float* __restrict__ out) {
  const int t = threadIdx.x;
  __shared__ float pooled[4][64];
  int b = t >> 6, d = t & 63;
  float s = 0.f;
  for (int lb = 0; lb < 32; ++lb) s += pp[(b * 32 + lb) * 64 + d];
  pooled[b][d] = s * (1.f / 4096.f);
  __syncthreads();
  if (t < 24) {
    int bb = t / 6, o = t - bb * 6;
    float acc = bc[o];
    for (int d2 = 0; d2 < 64; ++d2) acc += pooled[bb][d2] * wc[o * 64 + d2];
    out[bb * 6 + o] = acc;
  }
}

extern "C" void kernel_launch(void* const* d_in, const int* in_sizes, int n_in,
                              void* d_out, int out_size, void* d_ws, size_t ws_size,
                              hipStream_t stream) {
  const float* x    = (const float*)d_in[0];
  const float* w_in = (const float*)d_in[1];
  const float* b_in = (const float*)d_in[2];
  const float* ipw  = (const float*)d_in[3];
  const float* cw   = (const float*)d_in[4];
  const float* cb   = (const float*)d_in[5];
  const float* xpw  = (const float*)d_in[6];
  const float* dpw  = (const float*)d_in[7];
  const float* dpb  = (const float*)d_in[8];
  const float* Alog = (const float*)d_in[9];
  const float* Dsk  = (const float*)d_in[10];
  const float* opw  = (const float*)d_in[11];
  const float* wc   = (const float*)d_in[12];
  const float* bc   = (const float*)d_in[13];
  float* out = (float*)d_out;

  float* ws  = (float*)d_ws;
  float* h   = ws;                    // 1048576
  float* xp  = h + 1048576;           // 2097152 (reused as y in scan3)
  float* zb  = xp + 2097152;          // 2097152
  float* ub  = zb + 2097152;          // 2097152
  float* dl  = ub + 2097152;          // 2097152
  float* Bb  = dl + 2097152;          // 262144
  float* Cb  = Bb + 262144;           // 262144
  float* chP = Cb + 262144;           // 524288
  float* chH = chP + 524288;          // 524288
  float* cin = chH + 524288;          // 524288
  float* pp  = cin + 524288;          // 8192

  k_linin<<<256, 256, 0, stream>>>(x, w_in, b_in, h);
  for (int i = 0; i < 2; ++i) {
    k_inproj<<<dim3(256, 4), 256, 0, stream>>>(h, ipw + i * 16384, xp, zb);
    k_conv<<<8192, 256, 0, stream>>>(xp, cw + i * 512, cb + i * 128, ub);
    k_xproj<<<512, 256, 0, stream>>>(ub, xpw + i * 4608, dpw + i * 512, dpb + i * 128, dl, Bb, Cb);
    k_scan1<<<128, 256, 0, stream>>>(dl, ub, Bb, Alog + i * 2048, chP, chH);
    k_scan2<<<32, 256, 0, stream>>>(chP, chH, cin);
    k_scan3<<<128, 256, 0, stream>>>(dl, ub, Bb, Cb, zb, cin, Alog + i * 2048, Dsk + i * 128, xp);
    k_outproj<<<256, 256, 0, stream>>>(xp, opw + i * 8192, h);
  }
  k_poolpart<<<dim3(32, 4), 256, 0, stream>>>(h, pp);
  k_cls<<<1, 256, 0, stream>>>(pp, wc, bc, out);
}

// Round 2
// 353.844 us; speedup vs baseline: 1.1203x; 1.1203x over previous
//
#include <hip/hip_runtime.h>

// TinyMambaMulti: B=4, L=4096, D_MODEL=64, D_INNER=128, D_STATE=16, DT_RANK=4,
// D_CONV=4, N_LAYERS=2, OUT=6. All fp32.

#define NB 4
#define SL 4096
#define BLR (NB*SL)      // 16384 rows
#define NC 256           // scan chunks per sequence
#define CT 16            // steps per chunk (NC*CT == SL)

__device__ __forceinline__ float siluf(float x) { return x / (1.f + __expf(-x)); }
__device__ __forceinline__ float softplusf(float x) { return x > 20.f ? x : log1pf(__expf(x)); }

// ---------------- linear_in: h[r][64] = x[r][57] @ w[64][57]^T + b ----------------
__global__ __launch_bounds__(256) void k_linin(const float* __restrict__ x, const float* __restrict__ w,
                                               const float* __restrict__ bias, float* __restrict__ h) {
  __shared__ __align__(16) float xs[64][60];
  __shared__ __align__(16) float ws[64][60];
  const int t = threadIdx.x;
  const int r0 = blockIdx.x * 64;
  for (int i = t; i < 64 * 57; i += 256) {
    int r = i / 57, k = i - r * 57;
    xs[r][k] = x[(r0 + r) * 57 + k];
    ws[r][k] = w[i];
  }
  for (int i = t; i < 64 * 3; i += 256) {
    int r = i / 3, j = i - r * 3;
    xs[r][57 + j] = 0.f;
    ws[r][57 + j] = 0.f;
  }
  __syncthreads();
  const int col = t & 63;
  const int rg = t >> 6;   // 4 row groups of 16 rows
  float wreg[15][4];
#pragma unroll
  for (int k4 = 0; k4 < 15; ++k4) {
    float4 v = *(const float4*)&ws[col][k4 * 4];
    wreg[k4][0] = v.x; wreg[k4][1] = v.y; wreg[k4][2] = v.z; wreg[k4][3] = v.w;
  }
  const float bcol = bias[col];
  for (int g = 0; g < 4; ++g) {
    const int rb = rg * 16 + g * 4;
    float acc[4] = {bcol, bcol, bcol, bcol};
#pragma unroll
    for (int k4 = 0; k4 < 15; ++k4) {
#pragma unroll
      for (int i = 0; i < 4; ++i) {
        float4 xv = *(const float4*)&xs[rb + i][k4 * 4];
        acc[i] = fmaf(xv.x, wreg[k4][0], acc[i]);
        acc[i] = fmaf(xv.y, wreg[k4][1], acc[i]);
        acc[i] = fmaf(xv.z, wreg[k4][2], acc[i]);
        acc[i] = fmaf(xv.w, wreg[k4][3], acc[i]);
      }
    }
#pragma unroll
    for (int i = 0; i < 4; ++i) h[(r0 + rb + i) * 64 + col] = acc[i];
  }
}

// ---------------- in_proj: [16384x256] = h[16384x64] @ W[256x64]^T, split xp/z ----------------
__global__ __launch_bounds__(256) void k_inproj(const float* __restrict__ hin, const float* __restrict__ W,
                                                float* __restrict__ xp, float* __restrict__ z) {
  __shared__ __align__(16) float ht[64][68];
  __shared__ __align__(16) float wt[64][68];
  const int t = threadIdx.x;
  const int r0 = blockIdx.x * 64;
  const int c0 = blockIdx.y * 64;
  for (int idx = t; idx < 64 * 16; idx += 256) {
    int r = idx >> 4, k4 = idx & 15;
    float4 v = *(const float4*)(hin + (r0 + r) * 64 + 4 * k4);
    ht[4 * k4 + 0][r] = v.x; ht[4 * k4 + 1][r] = v.y; ht[4 * k4 + 2][r] = v.z; ht[4 * k4 + 3][r] = v.w;
  }
  for (int idx = t; idx < 64 * 16; idx += 256) {
    int c = idx >> 4, k4 = idx & 15;
    float4 v = *(const float4*)(W + (c0 + c) * 64 + 4 * k4);
    wt[4 * k4 + 0][c] = v.x; wt[4 * k4 + 1][c] = v.y; wt[4 * k4 + 2][c] = v.z; wt[4 * k4 + 3][c] = v.w;
  }
  __syncthreads();
  const int tc = t & 15, tr = t >> 4;
  float acc[4][4] = {};
  for (int k = 0; k < 64; ++k) {
    float4 a = *(const float4*)&ht[k][4 * tr];
    float4 b = *(const float4*)&wt[k][4 * tc];
    float av[4] = {a.x, a.y, a.z, a.w};
    float bv[4] = {b.x, b.y, b.z, b.w};
#pragma unroll
    for (int i = 0; i < 4; ++i)
#pragma unroll
      for (int j = 0; j < 4; ++j) acc[i][j] = fmaf(av[i], bv[j], acc[i][j]);
  }
#pragma unroll
  for (int i = 0; i < 4; ++i) {
    int row = r0 + 4 * tr + i;
    int c = c0 + 4 * tc;
    float4 v = make_float4(acc[i][0], acc[i][1], acc[i][2], acc[i][3]);
    if (c0 < 128) *(float4*)(xp + row * 128 + c) = v;
    else          *(float4*)(z + row * 128 + (c - 128)) = v;
  }
}

// ---------------- depthwise causal conv (k=4) + silu ----------------
__global__ __launch_bounds__(256) void k_conv(const float* __restrict__ xp, const float* __restrict__ cw,
                                              const float* __restrict__ cb, float* __restrict__ u) {
  int i = blockIdx.x * 256 + threadIdx.x;   // over BLR*128
  int d = i & 127;
  int row = i >> 7;
  int l = row & (SL - 1);
  const float4 wv = *(const float4*)(cw + d * 4);
  const float* base = xp + (size_t)row * 128 + d;
  float acc = cb[d] + base[0] * wv.w;
  if (l >= 1) acc += base[-128] * wv.z;
  if (l >= 2) acc += base[-256] * wv.y;
  if (l >= 3) acc += base[-384] * wv.x;
  u[i] = siluf(acc);
}

// ---------------- x_proj (36 outs) + dt_proj + softplus ----------------
__global__ __launch_bounds__(256) void k_xproj(const float* __restrict__ u, const float* __restrict__ xpw,
                                               const float* __restrict__ dpw, const float* __restrict__ dpb,
                                               float* __restrict__ delta, float* __restrict__ Bm,
                                               float* __restrict__ Cm) {
  __shared__ __align__(16) float us[32][132];
  __shared__ __align__(16) float ws[36][132];
  __shared__ float dbl[32][40];
  const int t = threadIdx.x;
  const int r0 = blockIdx.x * 32;
  for (int idx = t; idx < 32 * 32; idx += 256) {
    int r = idx >> 5, k4 = idx & 31;
    *(float4*)&us[r][4 * k4] = *(const float4*)(u + (size_t)(r0 + r) * 128 + 4 * k4);
  }
  for (int idx = t; idx < 36 * 32; idx += 256) {
    int c = idx >> 5, k4 = idx & 31;
    *(float4*)&ws[c][4 * k4] = *(const float4*)(xpw + c * 128 + 4 * k4);
  }
  __syncthreads();
  // dbl[32][36]: each task = 1 row x 4 cols
  for (int idx = t; idx < 32 * 9; idx += 256) {
    int r = idx / 9, cg = idx - r * 9;
    int c = cg * 4;
    float a0 = 0, a1 = 0, a2 = 0, a3 = 0;
#pragma unroll 8
    for (int k4 = 0; k4 < 32; ++k4) {
      float4 uu = *(const float4*)&us[r][4 * k4];
      float4 w0 = *(const float4*)&ws[c + 0][4 * k4];
      float4 w1 = *(const float4*)&ws[c + 1][4 * k4];
      float4 w2 = *(const float4*)&ws[c + 2][4 * k4];
      float4 w3 = *(const float4*)&ws[c + 3][4 * k4];
      a0 += uu.x * w0.x + uu.y * w0.y + uu.z * w0.z + uu.w * w0.w;
      a1 += uu.x * w1.x + uu.y * w1.y + uu.z * w1.z + uu.w * w1.w;
      a2 += uu.x * w2.x + uu.y * w2.y + uu.z * w2.z + uu.w * w2.w;
      a3 += uu.x * w3.x + uu.y * w3.y + uu.z * w3.z + uu.w * w3.w;
    }
    dbl[r][c + 0] = a0; dbl[r][c + 1] = a1; dbl[r][c + 2] = a2; dbl[r][c + 3] = a3;
  }
  __syncthreads();
  for (int idx = t; idx < 32 * 16; idx += 256) {
    int r = idx >> 4, n = idx & 15;
    int row = r0 + r;
    Bm[row * 16 + n] = dbl[r][4 + n];
    Cm[row * 16 + n] = dbl[r][20 + n];
  }
  for (int idx = t; idx < 32 * 128; idx += 256) {
    int r = idx >> 7, dd = idx & 127;
    float4 wv = *(const float4*)(dpw + dd * 4);
    float acc = dpb[dd] + dbl[r][0] * wv.x + dbl[r][1] * wv.y + dbl[r][2] * wv.z + dbl[r][3] * wv.w;
    delta[(size_t)(r0 + r) * 128 + dd] = softplusf(acc);
  }
}

// ---------------- scan phase 1: per-chunk decay product + local state ----------------
__global__ __launch_bounds__(256, 2) void k_scan1(const float* __restrict__ delta, const float* __restrict__ u,
                                                  const float* __restrict__ Bm, const float* __restrict__ Alog,
                                                  float* __restrict__ chP, float* __restrict__ chH) {
  int tid = blockIdx.x * 256 + threadIdx.x;      // 4*NC*128 = 131072
  const int d = tid & 127, c = (tid >> 7) & (NC - 1), b = tid >> 15;
  float A[16], hst[16];
  {
    float4 a0 = *(const float4*)(Alog + d * 16 + 0);
    float4 a1 = *(const float4*)(Alog + d * 16 + 4);
    float4 a2 = *(const float4*)(Alog + d * 16 + 8);
    float4 a3 = *(const float4*)(Alog + d * 16 + 12);
    float av[16] = {a0.x, a0.y, a0.z, a0.w, a1.x, a1.y, a1.z, a1.w,
                    a2.x, a2.y, a2.z, a2.w, a3.x, a3.y, a3.z, a3.w};
#pragma unroll
    for (int n = 0; n < 16; ++n) { A[n] = -__expf(av[n]); hst[n] = 0.f; }
  }
  const int rbase = b * SL + c * CT;
  float dtsum = 0.f;
#pragma unroll 4
  for (int tt = 0; tt < CT; ++tt) {
    int row = rbase + tt;
    float dt = delta[(size_t)row * 128 + d];
    float du = dt * u[(size_t)row * 128 + d];
    float4 B0 = *(const float4*)(Bm + row * 16 + 0);
    float4 B1 = *(const float4*)(Bm + row * 16 + 4);
    float4 B2 = *(const float4*)(Bm + row * 16 + 8);
    float4 B3 = *(const float4*)(Bm + row * 16 + 12);
    float Bv[16] = {B0.x, B0.y, B0.z, B0.w, B1.x, B1.y, B1.z, B1.w,
                    B2.x, B2.y, B2.z, B2.w, B3.x, B3.y, B3.z, B3.w};
    dtsum += dt;
#pragma unroll
    for (int n = 0; n < 16; ++n) {
      float a = __expf(dt * A[n]);
      hst[n] = fmaf(a, hst[n], du * Bv[n]);
    }
  }
  int off = ((b * 128 + d) * NC + c) * 16;
#pragma unroll
  for (int n4 = 0; n4 < 4; ++n4) {
    // chunk decay product: prod_t exp(dt_t*A) = exp(A * sum(dt))
    float p0 = __expf(dtsum * A[4 * n4 + 0]);
    float p1 = __expf(dtsum * A[4 * n4 + 1]);
    float p2 = __expf(dtsum * A[4 * n4 + 2]);
    float p3 = __expf(dtsum * A[4 * n4 + 3]);
    *(float4*)(chP + off + 4 * n4) = make_float4(p0, p1, p2, p3);
    *(float4*)(chH + off + 4 * n4) = make_float4(hst[4 * n4], hst[4 * n4 + 1], hst[4 * n4 + 2], hst[4 * n4 + 3]);
  }
}

// ---------------- scan phase 2: carry propagation across chunks (in-place: chHC -> carry-in) ----------------
__global__ __launch_bounds__(256) void k_scan2(const float* __restrict__ chP, float* chHC) {
  int tid = blockIdx.x * 256 + threadIdx.x;  // 8192
  int n = tid & 15, d = (tid >> 4) & 127, b = tid >> 11;
  float carry = 0.f;
  int base = (b * 128 + d) * NC * 16 + n;
#pragma unroll 8
  for (int c = 0; c < NC; ++c) {
    int idx = base + c * 16;
    float P = chP[idx];
    float H = chHC[idx];
    chHC[idx] = carry;                 // carry-in for chunk c
    carry = fmaf(P, carry, H);
  }
}

// ---------------- scan phase 3: replay with carry, emit y = (scan + u*D) * silu(z) ----------------
__global__ __launch_bounds__(256, 2) void k_scan3(const float* __restrict__ delta, const float* __restrict__ u,
                                                  const float* __restrict__ Bm, const float* __restrict__ Cm,
                                                  const float* __restrict__ zb, const float* __restrict__ cin,
                                                  const float* __restrict__ Alog, const float* __restrict__ Dsk,
                                                  float* __restrict__ y) {
  int tid = blockIdx.x * 256 + threadIdx.x;
  const int d = tid & 127, c = (tid >> 7) & (NC - 1), b = tid >> 15;
  float A[16], hst[16];
  {
    float4 a0 = *(const float4*)(Alog + d * 16 + 0);
    float4 a1 = *(const float4*)(Alog + d * 16 + 4);
    float4 a2 = *(const float4*)(Alog + d * 16 + 8);
    float4 a3 = *(const float4*)(Alog + d * 16 + 12);
    float av[16] = {a0.x, a0.y, a0.z, a0.w, a1.x, a1.y, a1.z, a1.w,
                    a2.x, a2.y, a2.z, a2.w, a3.x, a3.y, a3.z, a3.w};
#pragma unroll
    for (int n = 0; n < 16; ++n) A[n] = -__expf(av[n]);
  }
  int off = ((b * 128 + d) * NC + c) * 16;
  {
    float4 h0 = *(const float4*)(cin + off + 0);
    float4 h1 = *(const float4*)(cin + off + 4);
    float4 h2 = *(const float4*)(cin + off + 8);
    float4 h3 = *(const float4*)(cin + off + 12);
    hst[0] = h0.x; hst[1] = h0.y; hst[2] = h0.z; hst[3] = h0.w;
    hst[4] = h1.x; hst[5] = h1.y; hst[6] = h1.z; hst[7] = h1.w;
    hst[8] = h2.x; hst[9] = h2.y; hst[10] = h2.z; hst[11] = h2.w;
    hst[12] = h3.x; hst[13] = h3.y; hst[14] = h3.z; hst[15] = h3.w;
  }
  const float Dd = Dsk[d];
  const int rbase = b * SL + c * CT;
#pragma unroll 4
  for (int tt = 0; tt < CT; ++tt) {
    int row = rbase + tt;
    float dt = delta[(size_t)row * 128 + d];
    float ut = u[(size_t)row * 128 + d];
    float du = dt * ut;
    float4 B0 = *(const float4*)(Bm + row * 16 + 0);
    float4 B1 = *(const float4*)(Bm + row * 16 + 4);
    float4 B2 = *(const float4*)(Bm + row * 16 + 8);
    float4 B3 = *(const float4*)(Bm + row * 16 + 12);
    float4 C0 = *(const float4*)(Cm + row * 16 + 0);
    float4 C1 = *(const float4*)(Cm + row * 16 + 4);
    float4 C2 = *(const float4*)(Cm + row * 16 + 8);
    float4 C3 = *(const float4*)(Cm + row * 16 + 12);
    float Bv[16] = {B0.x, B0.y, B0.z, B0.w, B1.x, B1.y, B1.z, B1.w,
                    B2.x, B2.y, B2.z, B2.w, B3.x, B3.y, B3.z, B3.w};
    float Cv[16] = {C0.x, C0.y, C0.z, C0.w, C1.x, C1.y, C1.z, C1.w,
                    C2.x, C2.y, C2.z, C2.w, C3.x, C3.y, C3.z, C3.w};
    float yt = 0.f;
#pragma unroll
    for (int n = 0; n < 16; ++n) {
      float a = __expf(dt * A[n]);
      hst[n] = fmaf(a, hst[n], du * Bv[n]);
      yt = fmaf(hst[n], Cv[n], yt);
    }
    float zv = zb[(size_t)row * 128 + d];
    y[(size_t)row * 128 + d] = (yt + ut * Dd) * siluf(zv);
  }
}

// ---------------- out_proj (K=128 -> 64) with residual accumulate into h ----------------
__global__ __launch_bounds__(256) void k_outproj(const float* __restrict__ y, const float* __restrict__ W,
                                                 float* __restrict__ hio) {
  __shared__ __align__(16) float yt[128][68];
  __shared__ __align__(16) float wt[128][68];
  const int t = threadIdx.x;
  const int r0 = blockIdx.x * 64;
  for (int idx = t; idx < 64 * 32; idx += 256) {
    int r = idx >> 5, k4 = idx & 31;
    float4 v = *(const float4*)(y + (size_t)(r0 + r) * 128 + 4 * k4);
    yt[4 * k4 + 0][r] = v.x; yt[4 * k4 + 1][r] = v.y; yt[4 * k4 + 2][r] = v.z; yt[4 * k4 + 3][r] = v.w;
  }
  for (int idx = t; idx < 64 * 32; idx += 256) {
    int c = idx >> 5, k4 = idx & 31;
    float4 v = *(const float4*)(W + c * 128 + 4 * k4);
    wt[4 * k4 + 0][c] = v.x; wt[4 * k4 + 1][c] = v.y; wt[4 * k4 + 2][c] = v.z; wt[4 * k4 + 3][c] = v.w;
  }
  __syncthreads();
  const int tc = t & 15, tr = t >> 4;
  float acc[4][4] = {};
  for (int k = 0; k < 128; ++k) {
    float4 a = *(const float4*)&yt[k][4 * tr];
    float4 b = *(const float4*)&wt[k][4 * tc];
    float av[4] = {a.x, a.y, a.z, a.w};
    float bv[4] = {b.x, b.y, b.z, b.w};
#pragma unroll
    for (int i = 0; i < 4; ++i)
#pragma unroll
      for (int j = 0; j < 4; ++j) acc[i][j] = fmaf(av[i], bv[j], acc[i][j]);
  }
#pragma unroll
  for (int i = 0; i < 4; ++i) {
    int row = r0 + 4 * tr + i;
    float4* p = (float4*)(hio + row * 64 + 4 * tc);
    float4 old = *p;
    *p = make_float4(old.x + acc[i][0], old.y + acc[i][1], old.z + acc[i][2], old.w + acc[i][3]);
  }
}

// ---------------- pooling partials over L ----------------
__global__ __launch_bounds__(256) void k_poolpart(const float* __restrict__ h, float* __restrict__ pp) {
  const int lb = blockIdx.x;   // 0..31
  const int b = blockIdx.y;    // 0..3
  const int t = threadIdx.x;
  const int d = t & 63, part = t >> 6;
  float s = 0.f;
  for (int i = 0; i < 32; ++i) {
    int l = lb * 128 + part + i * 4;
    s += h[(size_t)(b * SL + l) * 64 + d];
  }
  __shared__ float red[256];
  red[t] = s;
  __syncthreads();
  if (t < 64) pp[(b * 32 + lb) * 64 + t] = red[t] + red[t + 64] + red[t + 128] + red[t + 192];
}

// ---------------- final reduce + classifier ----------------
__global__ __launch_bounds__(256) void k_cls(const float* __restrict__ pp, const float* __restrict__ wc,
                                             const float* __restrict__ bc, float* __restrict__ out) {
  const int t = threadIdx.x;
  __shared__ float pooled[4][64];
  int b = t >> 6, d = t & 63;
  float s = 0.f;
  for (int lb = 0; lb < 32; ++lb) s += pp[(b * 32 + lb) * 64 + d];
  pooled[b][d] = s * (1.f / 4096.f);
  __syncthreads();
  if (t < 24) {
    int bb = t / 6, o = t - bb * 6;
    float acc = bc[o];
    for (int d2 = 0; d2 < 64; ++d2) acc += pooled[bb][d2] * wc[o * 64 + d2];
    out[bb * 6 + o] = acc;
  }
}

extern "C" void kernel_launch(void* const* d_in, const int* in_sizes, int n_in,
                              void* d_out, int out_size, void* d_ws, size_t ws_size,
                              hipStream_t stream) {
  const float* x    = (const float*)d_in[0];
  const float* w_in = (const float*)d_in[1];
  const float* b_in = (const float*)d_in[2];
  const float* ipw  = (const float*)d_in[3];
  const float* cw   = (const float*)d_in[4];
  const float* cb   = (const float*)d_in[5];
  const float* xpw  = (const float*)d_in[6];
  const float* dpw  = (const float*)d_in[7];
  const float* dpb  = (const float*)d_in[8];
  const float* Alog = (const float*)d_in[9];
  const float* Dsk  = (const float*)d_in[10];
  const float* opw  = (const float*)d_in[11];
  const float* wc   = (const float*)d_in[12];
  const float* bc   = (const float*)d_in[13];
  float* out = (float*)d_out;

  float* ws  = (float*)d_ws;
  float* h   = ws;                    // 1048576
  float* xp  = h + 1048576;           // 2097152 (reused as y in scan3)
  float* zb  = xp + 2097152;          // 2097152
  float* ub  = zb + 2097152;          // 2097152
  float* dl  = ub + 2097152;          // 2097152
  float* Bb  = dl + 2097152;          // 262144
  float* Cb  = Bb + 262144;           // 262144
  float* chP = Cb + 262144;           // 2097152 (4*128*NC*16)
  float* chH = chP + 2097152;         // 2097152 (also carry-in after k_scan2, in-place)
  float* pp  = chH + 2097152;         // 8192

  k_linin<<<256, 256, 0, stream>>>(x, w_in, b_in, h);
  for (int i = 0; i < 2; ++i) {
    k_inproj<<<dim3(256, 4), 256, 0, stream>>>(h, ipw + i * 16384, xp, zb);
    k_conv<<<8192, 256, 0, stream>>>(xp, cw + i * 512, cb + i * 128, ub);
    k_xproj<<<512, 256, 0, stream>>>(ub, xpw + i * 4608, dpw + i * 512, dpb + i * 128, dl, Bb, Cb);
    k_scan1<<<512, 256, 0, stream>>>(dl, ub, Bb, Alog + i * 2048, chP, chH);
    k_scan2<<<32, 256, 0, stream>>>(chP, chH);
    k_scan3<<<512, 256, 0, stream>>>(dl, ub, Bb, Cb, zb, chH, Alog + i * 2048, Dsk + i * 128, xp);
    k_outproj<<<256, 256, 0, stream>>>(xp, opw + i * 8192, h);
  }
  k_poolpart<<<dim3(32, 4), 256, 0, stream>>>(h, pp);
  k_cls<<<1, 256, 0, stream>>>(pp, wc, bc, out);
}

// Round 4
// 248.794 us; speedup vs baseline: 1.5933x; 1.4222x over previous
//
#include <hip/hip_runtime.h>

// TinyMambaMulti: B=4, L=4096, D_MODEL=64, D_INNER=128, D_STATE=16, DT_RANK=4,
// D_CONV=4, N_LAYERS=2, OUT=6. All fp32.

#define NB 4
#define SL 4096
#define NC 256           // scan chunks per sequence
#define CT 16            // steps per chunk (NC*CT == SL)

__device__ __forceinline__ float siluf(float x) { return x / (1.f + __expf(-x)); }
__device__ __forceinline__ float softplusf(float x) { return x > 20.f ? x : log1pf(__expf(x)); }

// ---------------- prep: transpose out_proj_w [2][64][128] -> opwT [2][128][64] ----------------
__global__ __launch_bounds__(256) void k_prep(const float* __restrict__ opw, float* __restrict__ opwT) {
  int i = blockIdx.x * 256 + threadIdx.x;   // 16384
  int l = i >> 13;
  int rem = i & 8191;
  int d = rem >> 6, m = rem & 63;
  opwT[i] = opw[l * 8192 + m * 128 + d];
}

// ---------------- linear_in: h[r][64] = x[r][57] @ w[64][57]^T + b ----------------
__global__ __launch_bounds__(256) void k_linin(const float* __restrict__ x, const float* __restrict__ w,
                                               const float* __restrict__ bias, float* __restrict__ h) {
  __shared__ __align__(16) float xs[64][60];
  __shared__ __align__(16) float ws[64][60];
  const int t = threadIdx.x;
  const int r0 = blockIdx.x * 64;
  for (int i = t; i < 64 * 57; i += 256) {
    int r = i / 57, k = i - r * 57;
    xs[r][k] = x[(r0 + r) * 57 + k];
    ws[r][k] = w[i];
  }
  for (int i = t; i < 64 * 3; i += 256) {
    int r = i / 3, j = i - r * 3;
    xs[r][57 + j] = 0.f;
    ws[r][57 + j] = 0.f;
  }
  __syncthreads();
  const int col = t & 63;
  const int rg = t >> 6;
  float wreg[15][4];
#pragma unroll
  for (int k4 = 0; k4 < 15; ++k4) {
    float4 v = *(const float4*)&ws[col][k4 * 4];
    wreg[k4][0] = v.x; wreg[k4][1] = v.y; wreg[k4][2] = v.z; wreg[k4][3] = v.w;
  }
  const float bcol = bias[col];
  for (int g = 0; g < 4; ++g) {
    const int rb = rg * 16 + g * 4;
    float acc[4] = {bcol, bcol, bcol, bcol};
#pragma unroll
    for (int k4 = 0; k4 < 15; ++k4) {
#pragma unroll
      for (int i = 0; i < 4; ++i) {
        float4 xv = *(const float4*)&xs[rb + i][k4 * 4];
        acc[i] = fmaf(xv.x, wreg[k4][0], acc[i]);
        acc[i] = fmaf(xv.y, wreg[k4][1], acc[i]);
        acc[i] = fmaf(xv.z, wreg[k4][2], acc[i]);
        acc[i] = fmaf(xv.w, wreg[k4][3], acc[i]);
      }
    }
#pragma unroll
    for (int i = 0; i < 4; ++i) h[(r0 + rb + i) * 64 + col] = acc[i];
  }
}

// ---------------- in_proj: [16384x256] = h[16384x64] @ W[256x64]^T, split xp/z ----------------
__global__ __launch_bounds__(256) void k_inproj(const float* __restrict__ hin, const float* __restrict__ W,
                                                float* __restrict__ xp, float* __restrict__ z) {
  __shared__ __align__(16) float ht[64][68];
  __shared__ __align__(16) float wt[64][68];
  const int t = threadIdx.x;
  const int r0 = blockIdx.x * 64;
  const int c0 = blockIdx.y * 64;
  for (int idx = t; idx < 64 * 16; idx += 256) {
    int r = idx >> 4, k4 = idx & 15;
    float4 v = *(const float4*)(hin + (r0 + r) * 64 + 4 * k4);
    ht[4 * k4 + 0][r] = v.x; ht[4 * k4 + 1][r] = v.y; ht[4 * k4 + 2][r] = v.z; ht[4 * k4 + 3][r] = v.w;
  }
  for (int idx = t; idx < 64 * 16; idx += 256) {
    int c = idx >> 4, k4 = idx & 15;
    float4 v = *(const float4*)(W + (c0 + c) * 64 + 4 * k4);
    wt[4 * k4 + 0][c] = v.x; wt[4 * k4 + 1][c] = v.y; wt[4 * k4 + 2][c] = v.z; wt[4 * k4 + 3][c] = v.w;
  }
  __syncthreads();
  const int tc = t & 15, tr = t >> 4;
  float acc[4][4] = {};
  for (int k = 0; k < 64; ++k) {
    float4 a = *(const float4*)&ht[k][4 * tr];
    float4 b = *(const float4*)&wt[k][4 * tc];
    float av[4] = {a.x, a.y, a.z, a.w};
    float bv[4] = {b.x, b.y, b.z, b.w};
#pragma unroll
    for (int i = 0; i < 4; ++i)
#pragma unroll
      for (int j = 0; j < 4; ++j) acc[i][j] = fmaf(av[i], bv[j], acc[i][j]);
  }
#pragma unroll
  for (int i = 0; i < 4; ++i) {
    int row = r0 + 4 * tr + i;
    int c = c0 + 4 * tc;
    float4 v = make_float4(acc[i][0], acc[i][1], acc[i][2], acc[i][3]);
    if (c0 < 128) *(float4*)(xp + row * 128 + c) = v;
    else          *(float4*)(z + row * 128 + (c - 128)) = v;
  }
}

// ---------------- K_mid: conv+silu + x_proj + dt_proj + scan-local, per 16-row chunk ----------------
__global__ __launch_bounds__(256, 3) void k_mid(const float* __restrict__ xp, const float* __restrict__ cw,
                                                const float* __restrict__ cb, const float* __restrict__ xpw,
                                                const float* __restrict__ dpw, const float* __restrict__ dpb,
                                                const float* __restrict__ Alog,
                                                float* __restrict__ u_g, float* __restrict__ dl_g,
                                                float* __restrict__ B_g, float* __restrict__ C_g,
                                                float* __restrict__ chP, float* __restrict__ chH) {
  __shared__ __align__(16) float xpsh[19][132];
  __shared__ __align__(16) float ush[16][132];
  __shared__ __align__(16) float dsh[16][132];
  __shared__ __align__(16) float wsh[36][132];
  __shared__ __align__(16) float dbl[16][40];
  __shared__ float bsh[16][16];
  __shared__ float csh[16][16];

  const int t = threadIdx.x;
  const int c = blockIdx.x;          // chunk 0..255
  const int b = blockIdx.y;          // batch 0..3
  const int r0 = c * CT;
  const int grow0 = b * SL + r0;

  // P0: stage xp rows [r0-3, r0+16) and x_proj_w
  for (int i = t; i < 19 * 128; i += 256) {
    int r = i >> 7, d = i & 127;
    float v = 0.f;
    if (!(c == 0 && r < 3)) v = xp[(size_t)(grow0 - 3 + r) * 128 + d];
    xpsh[r][d] = v;
  }
  for (int i = t; i < 36 * 128; i += 256) {
    int cc = i >> 7, d = i & 127;
    wsh[cc][d] = xpw[cc * 128 + d];
  }
  __syncthreads();

  // P1: conv + silu -> u
  for (int i = t; i < 16 * 128; i += 256) {
    int r = i >> 7, d = i & 127;
    float4 cwv = *(const float4*)(cw + d * 4);
    float val = cb[d] + xpsh[r][d] * cwv.x + xpsh[r + 1][d] * cwv.y +
                xpsh[r + 2][d] * cwv.z + xpsh[r + 3][d] * cwv.w;
    float uu = siluf(val);
    ush[r][d] = uu;
    u_g[(size_t)(grow0 + r) * 128 + d] = uu;
  }
  __syncthreads();

  // P2: x_proj -> dbl[16][36]
  if (t < 144) {
    int r = t / 9, cg = t - (t / 9) * 9;
    int cc = cg * 4;
    float a0 = 0, a1 = 0, a2 = 0, a3 = 0;
#pragma unroll 8
    for (int k4 = 0; k4 < 32; ++k4) {
      float4 uu = *(const float4*)&ush[r][4 * k4];
      float4 w0 = *(const float4*)&wsh[cc + 0][4 * k4];
      float4 w1 = *(const float4*)&wsh[cc + 1][4 * k4];
      float4 w2 = *(const float4*)&wsh[cc + 2][4 * k4];
      float4 w3 = *(const float4*)&wsh[cc + 3][4 * k4];
      a0 += uu.x * w0.x + uu.y * w0.y + uu.z * w0.z + uu.w * w0.w;
      a1 += uu.x * w1.x + uu.y * w1.y + uu.z * w1.z + uu.w * w1.w;
      a2 += uu.x * w2.x + uu.y * w2.y + uu.z * w2.z + uu.w * w2.w;
      a3 += uu.x * w3.x + uu.y * w3.y + uu.z * w3.z + uu.w * w3.w;
    }
    dbl[r][cc + 0] = a0; dbl[r][cc + 1] = a1; dbl[r][cc + 2] = a2; dbl[r][cc + 3] = a3;
  }
  __syncthreads();

  // P3: dt_proj + softplus -> delta; split B/C
  for (int i = t; i < 16 * 128; i += 256) {
    int r = i >> 7, d = i & 127;
    float4 wv = *(const float4*)(dpw + d * 4);
    float acc = dpb[d] + dbl[r][0] * wv.x + dbl[r][1] * wv.y + dbl[r][2] * wv.z + dbl[r][3] * wv.w;
    float dt = softplusf(acc);
    dsh[r][d] = dt;
    dl_g[(size_t)(grow0 + r) * 128 + d] = dt;
  }
  for (int i = t; i < 16 * 32; i += 256) {
    int r = i >> 5, j = i & 31;
    float v = dbl[r][4 + j];
    if (j < 16) { bsh[r][j] = v; B_g[(grow0 + r) * 16 + j] = v; }
    else        { csh[r][j - 16] = v; C_g[(grow0 + r) * 16 + (j - 16)] = v; }
  }
  __syncthreads();

  // P4: chunk-local scan (thread = (d, half); 8 states each)
  {
    const int d = t & 127, hf = t >> 7, n0 = hf * 8;
    float a[8], hst[8];
#pragma unroll
    for (int j = 0; j < 8; ++j) {
      a[j] = -__expf(Alog[d * 16 + n0 + j]);
      hst[j] = 0.f;
    }
    float dts = 0.f;
#pragma unroll 4
    for (int tt = 0; tt < CT; ++tt) {
      float dt = dsh[tt][d];
      float du = dt * ush[tt][d];
      dts += dt;
#pragma unroll
      for (int j = 0; j < 8; ++j) {
        float e = __expf(dt * a[j]);
        hst[j] = fmaf(e, hst[j], du * bsh[tt][n0 + j]);
      }
    }
    int off = ((b * 128 + d) * NC + c) * 16 + n0;
    float p[8];
#pragma unroll
    for (int j = 0; j < 8; ++j) p[j] = __expf(dts * a[j]);
    *(float4*)(chP + off + 0) = make_float4(p[0], p[1], p[2], p[3]);
    *(float4*)(chP + off + 4) = make_float4(p[4], p[5], p[6], p[7]);
    *(float4*)(chH + off + 0) = make_float4(hst[0], hst[1], hst[2], hst[3]);
    *(float4*)(chH + off + 4) = make_float4(hst[4], hst[5], hst[6], hst[7]);
  }
}

// ---------------- scan2p: two-level carry propagation, block per (b,d) ----------------
// thread (n, g): local summary over 16 chunks, Hillis-Steele compose over g, replay.
// In-place: chH becomes carry-in per chunk.
__global__ __launch_bounds__(256) void k_scan2p(const float* __restrict__ chP, float* chH) {
  __shared__ float sP[16][16];   // [g][n]
  __shared__ float sH[16][16];
  const int t = threadIdx.x;
  const int n = t & 15, g = t >> 4;
  const int d = blockIdx.x, b = blockIdx.y;
  const int base = ((b * 128 + d) * NC) * 16 + n;

  float Pl[16], Hl[16];
  float cp = 1.f, ch = 0.f;
#pragma unroll
  for (int i = 0; i < 16; ++i) {
    int idx = base + (g * 16 + i) * 16;
    float P = chP[idx];
    float H = chH[idx];
    Pl[i] = P; Hl[i] = H;
    ch = fmaf(P, ch, H);
    cp *= P;
  }
  sP[g][n] = cp; sH[g][n] = ch;
  __syncthreads();
#pragma unroll
  for (int s = 1; s < 16; s <<= 1) {
    float pL = 1.f, hL = 0.f;
    if (g >= s) { pL = sP[g - s][n]; hL = sH[g - s][n]; }
    __syncthreads();
    ch = fmaf(cp, hL, ch);   // op(left, current): H = curP*leftH + curH
    cp = cp * pL;
    sP[g][n] = cp; sH[g][n] = ch;
    __syncthreads();
  }
  float carry = 0.f;                       // exclusive prefix applied to h0 = 0
  if (g > 0) carry = sH[g - 1][n];
#pragma unroll
  for (int i = 0; i < 16; ++i) {
    int idx = base + (g * 16 + i) * 16;
    chH[idx] = carry;                      // carry-in for this chunk
    carry = fmaf(Pl[i], carry, Hl[i]);
  }
}

// ---------------- K_back: scan replay + D-skip + silu(z) gate + out_proj + residual ----------------
__global__ __launch_bounds__(256, 4) void k_back(const float* __restrict__ u_g, const float* __restrict__ dl_g,
                                                 const float* __restrict__ B_g, const float* __restrict__ C_g,
                                                 const float* __restrict__ z_g, const float* __restrict__ cin,
                                                 const float* __restrict__ Alog, const float* __restrict__ Dsk,
                                                 const float* __restrict__ opwT, float* __restrict__ h) {
  __shared__ __align__(16) float ush[16][132];
  __shared__ float bsh[16][16];
  __shared__ float csh[16][16];
  __shared__ __align__(16) char poolA[2560 * 4];   // dsh[16][132] (scan) -> ygsh[128][20] (gate/outproj)
  __shared__ __align__(16) char poolB[4224 * 4];   // ysh[2][16][132] (scan) -> psh[4][16][64] (outproj)

  float* dsh  = (float*)poolA;     // [16][132]
  float* ygsh = (float*)poolA;     // [128][20] (after scan barrier)
  float* ysh  = (float*)poolB;     // [2][16][132]
  float* psh  = (float*)poolB;     // [4][16][64] (after gate barrier)

  const int t = threadIdx.x;
  const int c = blockIdx.x;
  const int b = blockIdx.y;
  const int r0 = c * CT;
  const int grow0 = b * SL + r0;

  // P0: stage u, delta, B, C
  for (int i = t; i < 16 * 128; i += 256) {
    int r = i >> 7, d = i & 127;
    ush[r][d] = u_g[(size_t)(grow0 + r) * 128 + d];
    dsh[r * 132 + d] = dl_g[(size_t)(grow0 + r) * 128 + d];
  }
  for (int i = t; i < 16 * 32; i += 256) {
    int r = i >> 5, j = i & 31;
    if (j < 16) bsh[r][j] = B_g[(grow0 + r) * 16 + j];
    else        csh[r][j - 16] = C_g[(grow0 + r) * 16 + (j - 16)];
  }
  __syncthreads();

  // P1: replay scan with carry-in (thread = (d, half))
  {
    const int d = t & 127, hf = t >> 7, n0 = hf * 8;
    float a[8], hst[8];
    int off = ((b * 128 + d) * NC + c) * 16 + n0;
    float4 h0 = *(const float4*)(cin + off + 0);
    float4 h1 = *(const float4*)(cin + off + 4);
    hst[0] = h0.x; hst[1] = h0.y; hst[2] = h0.z; hst[3] = h0.w;
    hst[4] = h1.x; hst[5] = h1.y; hst[6] = h1.z; hst[7] = h1.w;
#pragma unroll
    for (int j = 0; j < 8; ++j) a[j] = -__expf(Alog[d * 16 + n0 + j]);
#pragma unroll 4
    for (int tt = 0; tt < CT; ++tt) {
      float dt = dsh[tt * 132 + d];
      float du = dt * ush[tt][d];
      float yp = 0.f;
#pragma unroll
      for (int j = 0; j < 8; ++j) {
        float e = __expf(dt * a[j]);
        hst[j] = fmaf(e, hst[j], du * bsh[tt][n0 + j]);
        yp = fmaf(hst[j], csh[tt][n0 + j], yp);
      }
      ysh[(hf * 16 + tt) * 132 + d] = yp;
    }
  }
  __syncthreads();

  // P2: gate -> ygsh[d][r] (pad 20)
  for (int i = t; i < 16 * 128; i += 256) {
    int r = i >> 7, d = i & 127;
    float y = ysh[r * 132 + d] + ysh[(16 + r) * 132 + d] + ush[r][d] * Dsk[d];
    float zv = z_g[(size_t)(grow0 + r) * 128 + d];
    ygsh[d * 20 + r] = y * siluf(zv);
  }
  __syncthreads();

  // P3: out_proj partials: thread (o, q): rows 0..15, d in [q*32, q*32+32)
  {
    const int o = t & 63, q = t >> 6;
    float wreg[32];
#pragma unroll
    for (int j = 0; j < 32; ++j) wreg[j] = opwT[(q * 32 + j) * 64 + o];
    float acc[16] = {};
#pragma unroll 8
    for (int j = 0; j < 32; ++j) {
      int dd = q * 32 + j;
      const float4* yv = (const float4*)(ygsh + dd * 20);
      float4 y0 = yv[0], y1 = yv[1], y2 = yv[2], y3 = yv[3];
      float w = wreg[j];
      acc[0]  = fmaf(y0.x, w, acc[0]);  acc[1]  = fmaf(y0.y, w, acc[1]);
      acc[2]  = fmaf(y0.z, w, acc[2]);  acc[3]  = fmaf(y0.w, w, acc[3]);
      acc[4]  = fmaf(y1.x, w, acc[4]);  acc[5]  = fmaf(y1.y, w, acc[5]);
      acc[6]  = fmaf(y1.z, w, acc[6]);  acc[7]  = fmaf(y1.w, w, acc[7]);
      acc[8]  = fmaf(y2.x, w, acc[8]);  acc[9]  = fmaf(y2.y, w, acc[9]);
      acc[10] = fmaf(y2.z, w, acc[10]); acc[11] = fmaf(y2.w, w, acc[11]);
      acc[12] = fmaf(y3.x, w, acc[12]); acc[13] = fmaf(y3.y, w, acc[13]);
      acc[14] = fmaf(y3.z, w, acc[14]); acc[15] = fmaf(y3.w, w, acc[15]);
    }
    __syncthreads();   // ysh (poolB) dead; reuse as psh
#pragma unroll
    for (int r = 0; r < 16; ++r) psh[(q * 16 + r) * 64 + o] = acc[r];
  }
  __syncthreads();

  // P4: reduce partials + residual accumulate into h
  for (int i = t; i < 16 * 64; i += 256) {
    int r = i >> 6, o = i & 63;
    float s = psh[(0 * 16 + r) * 64 + o] + psh[(1 * 16 + r) * 64 + o] +
              psh[(2 * 16 + r) * 64 + o] + psh[(3 * 16 + r) * 64 + o];
    h[(size_t)(grow0 + r) * 64 + o] += s;
  }
}

// ---------------- pooling partials over L ----------------
__global__ __launch_bounds__(256) void k_poolpart(const float* __restrict__ h, float* __restrict__ pp) {
  const int lb = blockIdx.x;
  const int b = blockIdx.y;
  const int t = threadIdx.x;
  const int d = t & 63, part = t >> 6;
  float s = 0.f;
  for (int i = 0; i < 32; ++i) {
    int l = lb * 128 + part + i * 4;
    s += h[(size_t)(b * SL + l) * 64 + d];
  }
  __shared__ float red[256];
  red[t] = s;
  __syncthreads();
  if (t < 64) pp[(b * 32 + lb) * 64 + t] = red[t] + red[t + 64] + red[t + 128] + red[t + 192];
}

// ---------------- final reduce + classifier ----------------
__global__ __launch_bounds__(256) void k_cls(const float* __restrict__ pp, const float* __restrict__ wc,
                                             const float* __restrict__ bc, float* __restrict__ out) {
  const int t = threadIdx.x;
  __shared__ float pooled[4][64];
  int b = t >> 6, d = t & 63;
  float s = 0.f;
  for (int lb = 0; lb < 32; ++lb) s += pp[(b * 32 + lb) * 64 + d];
  pooled[b][d] = s * (1.f / 4096.f);
  __syncthreads();
  if (t < 24) {
    int bb = t / 6, o = t - bb * 6;
    float acc = bc[o];
    for (int d2 = 0; d2 < 64; ++d2) acc += pooled[bb][d2] * wc[o * 64 + d2];
    out[bb * 6 + o] = acc;
  }
}

extern "C" void kernel_launch(void* const* d_in, const int* in_sizes, int n_in,
                              void* d_out, int out_size, void* d_ws, size_t ws_size,
                              hipStream_t stream) {
  const float* x    = (const float*)d_in[0];
  const float* w_in = (const float*)d_in[1];
  const float* b_in = (const float*)d_in[2];
  const float* ipw  = (const float*)d_in[3];
  const float* cw   = (const float*)d_in[4];
  const float* cb   = (const float*)d_in[5];
  const float* xpw  = (const float*)d_in[6];
  const float* dpw  = (const float*)d_in[7];
  const float* dpb  = (const float*)d_in[8];
  const float* Alog = (const float*)d_in[9];
  const float* Dsk  = (const float*)d_in[10];
  const float* opw  = (const float*)d_in[11];
  const float* wc   = (const float*)d_in[12];
  const float* bc   = (const float*)d_in[13];
  float* out = (float*)d_out;

  float* ws   = (float*)d_ws;
  float* h    = ws;                    // 1048576
  float* xp   = h + 1048576;           // 2097152
  float* zb   = xp + 2097152;          // 2097152
  float* ub   = zb + 2097152;          // 2097152
  float* dl   = ub + 2097152;          // 2097152
  float* Bb   = dl + 2097152;          // 262144
  float* Cb   = Bb + 262144;           // 262144
  float* chP  = Cb + 262144;           // 2097152
  float* chH  = chP + 2097152;         // 2097152 (becomes carry-in after k_scan2p)
  float* opwT = chH + 2097152;         // 16384
  float* pp   = opwT + 16384;          // 8192

  k_prep<<<64, 256, 0, stream>>>(opw, opwT);
  k_linin<<<256, 256, 0, stream>>>(x, w_in, b_in, h);
  for (int i = 0; i < 2; ++i) {
    k_inproj<<<dim3(256, 4), 256, 0, stream>>>(h, ipw + i * 16384, xp, zb);
    k_mid<<<dim3(NC, 4), 256, 0, stream>>>(xp, cw + i * 512, cb + i * 128,
                                           xpw + i * 4608, dpw + i * 512, dpb + i * 128,
                                           Alog + i * 2048, ub, dl, Bb, Cb, chP, chH);
    k_scan2p<<<dim3(128, 4), 256, 0, stream>>>(chP, chH);
    k_back<<<dim3(NC, 4), 256, 0, stream>>>(ub, dl, Bb, Cb, zb, chH,
                                            Alog + i * 2048, Dsk + i * 128,
                                            opwT + i * 8192, h);
  }
  k_poolpart<<<dim3(32, 4), 256, 0, stream>>>(h, pp);
  k_cls<<<1, 256, 0, stream>>>(pp, wc, bc, out);
}